// Round 4
// baseline (448.802 us; speedup 1.0000x reference)
//
#include <hip/hip_runtime.h>
#include <hip/hip_bf16.h>
#include <type_traits>

#define BATCH 2
#define SEQ   8192
#define CH    1024
#define NH    16
#define BLK   64
#define WIN   192
#define NBL   128
#define DH    64
#define MR    (BATCH*SEQ)   // 16384

typedef __bf16 bf16x8 __attribute__((ext_vector_type(8)));
typedef float  f32x4  __attribute__((ext_vector_type(4)));

__device__ __forceinline__ f32x4 zero4() {
    f32x4 z; z[0]=0.f; z[1]=0.f; z[2]=0.f; z[3]=0.f; return z;
}

union Pack8 { __hip_bfloat16 h[8]; uint4 u; };

typedef const __attribute__((address_space(1))) unsigned int* gas_ptr;
typedef       __attribute__((address_space(3))) unsigned int* las_ptr;

__device__ __forceinline__ void gload_lds16(const __hip_bfloat16* g, __hip_bfloat16* l) {
    __builtin_amdgcn_global_load_lds((gas_ptr)(const void*)g, (las_ptr)(void*)l, 16, 0, 0);
}

__device__ __forceinline__ int xcd_swz(int bid, int nwg) {
    return (bid & 7) * (nwg >> 3) + (bid >> 3);
}

// ---- fp32 -> bf16 pack, 8 elements/thread
__global__ __launch_bounds__(256) void pack_bf16(
    const float* __restrict__ src, __hip_bfloat16* __restrict__ dst, int n8)
{
    int i = blockIdx.x * 256 + threadIdx.x;
    if (i >= n8) return;
    const float4* s = reinterpret_cast<const float4*>(src);
    float4 a = s[2 * i], b = s[2 * i + 1];
    Pack8 p;
    p.h[0] = __float2bfloat16(a.x); p.h[1] = __float2bfloat16(a.y);
    p.h[2] = __float2bfloat16(a.z); p.h[3] = __float2bfloat16(a.w);
    p.h[4] = __float2bfloat16(b.x); p.h[5] = __float2bfloat16(b.y);
    p.h[6] = __float2bfloat16(b.z); p.h[7] = __float2bfloat16(b.w);
    reinterpret_cast<uint4*>(dst)[i] = p.u;
}

// =====================================================================
// 256x256 GEMM, BK=64, 8 waves (2M x 4N), 4-phase-per-tile m201-style
// schedule: each phase = {issue ds_reads + 1 half-tile stage} -> barrier
// -> lgkmcnt(0) -> 16 MFMA (setprio-wrapped) -> [vmcnt gate] -> barrier.
// Reads for phase p issue right after barrier-2 of p-1, overlapping the
// still-executing MFMAs (barriers order issue, not completion).
//
// LDS (128 KiB, dbuf): A [buf][khalf][1024x16B] in [0,32768) elems,
// B same in [32768,65536).  Chunk c holds row r=c>>2, col-quad
// s=(c&3)^((r>>1)&3) (octet-bijective -> 0 bank conflicts, verified R3).
//
// Phase map per K-tile: (mh0,k0)(mh1,k0)(mh0,k1)(mh1,k1); B-frags of each
// kk register-held across the two m-half phases (reads 8/4/8/4 = 24/tile).
// Stages: one 16KB half-tile per phase, order A-klo,B-klo,A-khi,B-khi of
// tile t+1.  vmcnt(4) at end of p1 (gates khi(t): 8 in flight, oldest 4)
// and end of p3 (gates klo(t+1)) -- never drains to 0 in the main loop.
// =====================================================================

__device__ __forceinline__ void stage_half(
    const __hip_bfloat16* __restrict__ g, int goff,
    __hip_bfloat16* sm, int loff, int tid)
{
    gload_lds16(g + goff,            sm + loff + tid * 8);
    gload_lds16(g + goff + 128 * CH, sm + loff + (tid + 512) * 8);
}

#define SB0 __builtin_amdgcn_sched_barrier(0)
#define LGKM0 do { asm volatile("s_waitcnt lgkmcnt(0)" ::: "memory"); \
                   __builtin_amdgcn_sched_barrier(0); } while (0)
#define VMCNT(n) do { asm volatile("s_waitcnt vmcnt(" #n ")" ::: "memory"); \
                      __builtin_amdgcn_sched_barrier(0); } while (0)

template<int MH, bool RB>
__device__ __forceinline__ void phase_reads(
    const __hip_bfloat16* Ak, const __hip_bfloat16* Bk,
    int aoff, int boff, bf16x8 (&af)[4], bf16x8 (&bfk)[4])
{
    if constexpr (RB) {
        #pragma unroll
        for (int j = 0; j < 4; ++j)
            bfk[j] = *reinterpret_cast<const bf16x8*>(Bk + boff + j * 512);
    }
    #pragma unroll
    for (int i = 0; i < 4; ++i)
        af[i] = *reinterpret_cast<const bf16x8*>(Ak + aoff + (MH * 4 + i) * 512);
}

template<int MH>
__device__ __forceinline__ void phase_mfma16(
    const bf16x8 (&af)[4], const bf16x8 (&bfk)[4], f32x4 (&acc)[8][4])
{
    __builtin_amdgcn_s_setprio(1);
    #pragma unroll
    for (int i = 0; i < 4; ++i)
        #pragma unroll
        for (int j = 0; j < 4; ++j)
            acc[MH * 4 + i][j] = __builtin_amdgcn_mfma_f32_16x16x32_bf16(
                af[i], bfk[j], acc[MH * 4 + i][j], 0, 0, 0);
    __builtin_amdgcn_s_setprio(0);
}

template<typename OT>
__device__ __forceinline__ void gemm_body256(
    const __hip_bfloat16* __restrict__ A, const __hip_bfloat16* __restrict__ Wb,
    const float* __restrict__ bias, OT* __restrict__ out, float alpha,
    int m0, int n0, __hip_bfloat16* sm)
{
    const int tid  = threadIdx.x;
    const int wid  = tid >> 6;
    const int lane = tid & 63;
    const int quad = lane >> 4;
    const int l16  = lane & 15;
    const int wr   = wid >> 2, wc = wid & 3;   // 2 x 4 wave grid, 128x64 out each

    // staging: chunk c=tid -> row tid>>2, global seg (tid&3)^((tid>>3)&3);
    // chunk tid+512 -> row +128, same seg.
    const int r0 = tid >> 2;
    const int s0 = (tid & 3) ^ ((tid >> 3) & 3);
    const int offA0 = (m0 + r0) * CH + s0 * 8;
    const int offB0 = (n0 + r0) * CH + s0 * 8;

    // frag reads: row r -> chunk r*4 + (quad^((r>>1)&3))
    const int cq   = quad ^ ((l16 >> 1) & 3);
    const int aoff = ((wr * 128 + l16) * 4 + cq) * 8;
    const int boff = ((wc * 64  + l16) * 4 + cq) * 8;

    f32x4 acc[8][4];
    #pragma unroll
    for (int i = 0; i < 8; ++i)
        #pragma unroll
        for (int j = 0; j < 4; ++j) acc[i][j] = zero4();

    // ---- prologue: tile 0 -> buf 0, order A-klo, B-klo, A-khi, B-khi
    stage_half(A,  offA0,      sm, 0,             tid);
    stage_half(Wb, offB0,      sm, 32768,         tid);
    stage_half(A,  offA0 + 32, sm, 8192,          tid);
    stage_half(Wb, offB0 + 32, sm, 32768 + 8192,  tid);
    VMCNT(4);                       // klo(0) landed; khi(0) gated at p1(0)
    __builtin_amdgcn_s_barrier();
    SB0;

    bf16x8 af[4], bfk[4];

    #pragma unroll 1
    for (int t = 0; t < 15; ++t) {
        const int cur = t & 1, nb = cur ^ 1;
        const int kn  = (t + 1) * 64;
        const __hip_bfloat16* As_ = sm + cur * 16384;
        const __hip_bfloat16* Bs_ = sm + 32768 + cur * 16384;

        // p0: (mh0, k0); stage A-klo(t+1)
        phase_reads<0, true>(As_, Bs_, aoff, boff, af, bfk);
        stage_half(A, offA0 + kn, sm, nb * 16384, tid);
        SB0;
        __builtin_amdgcn_s_barrier();
        LGKM0;
        phase_mfma16<0>(af, bfk, acc);
        __builtin_amdgcn_s_barrier();

        // p1: (mh1, k0); stage B-klo(t+1); gate khi(t)
        phase_reads<1, false>(As_, Bs_, aoff, boff, af, bfk);
        stage_half(Wb, offB0 + kn, sm, 32768 + nb * 16384, tid);
        SB0;
        __builtin_amdgcn_s_barrier();
        LGKM0;
        phase_mfma16<1>(af, bfk, acc);
        VMCNT(4);
        __builtin_amdgcn_s_barrier();

        // p2: (mh0, k1); stage A-khi(t+1)
        phase_reads<0, true>(As_ + 8192, Bs_ + 8192, aoff, boff, af, bfk);
        stage_half(A, offA0 + kn + 32, sm, nb * 16384 + 8192, tid);
        SB0;
        __builtin_amdgcn_s_barrier();
        LGKM0;
        phase_mfma16<0>(af, bfk, acc);
        __builtin_amdgcn_s_barrier();

        // p3: (mh1, k1); stage B-khi(t+1); gate klo(t+1)
        phase_reads<1, false>(As_ + 8192, Bs_ + 8192, aoff, boff, af, bfk);
        stage_half(Wb, offB0 + kn + 32, sm, 32768 + nb * 16384 + 8192, tid);
        SB0;
        __builtin_amdgcn_s_barrier();
        LGKM0;
        phase_mfma16<1>(af, bfk, acc);
        VMCNT(4);
        __builtin_amdgcn_s_barrier();
    }

    // ---- peeled tail (t=15, cur=1): no staging
    {
        const __hip_bfloat16* As_ = sm + 16384;
        const __hip_bfloat16* Bs_ = sm + 32768 + 16384;

        phase_reads<0, true>(As_, Bs_, aoff, boff, af, bfk);
        SB0;
        __builtin_amdgcn_s_barrier();
        LGKM0;
        phase_mfma16<0>(af, bfk, acc);
        __builtin_amdgcn_s_barrier();

        phase_reads<1, false>(As_, Bs_, aoff, boff, af, bfk);
        SB0;
        __builtin_amdgcn_s_barrier();
        LGKM0;
        phase_mfma16<1>(af, bfk, acc);
        VMCNT(0);                    // khi(15) (last 4 outstanding)
        __builtin_amdgcn_s_barrier();

        phase_reads<0, true>(As_ + 8192, Bs_ + 8192, aoff, boff, af, bfk);
        SB0;
        __builtin_amdgcn_s_barrier();
        LGKM0;
        phase_mfma16<0>(af, bfk, acc);
        __builtin_amdgcn_s_barrier();

        phase_reads<1, false>(As_ + 8192, Bs_ + 8192, aoff, boff, af, bfk);
        SB0;
        __builtin_amdgcn_s_barrier();
        LGKM0;
        phase_mfma16<1>(af, bfk, acc);
    }

    // ---- epilogue
    #pragma unroll
    for (int j = 0; j < 4; ++j) {
        const int col = n0 + wc * 64 + j * 16 + l16;
        const float bv = bias[col];
        #pragma unroll
        for (int i = 0; i < 8; ++i) {
            #pragma unroll
            for (int r = 0; r < 4; ++r) {
                const int row = m0 + wr * 128 + i * 16 + quad * 4 + r;
                float v = alpha * (acc[i][j][r] + bv);
                if constexpr (std::is_same<OT, float>::value)
                    out[(size_t)row * CH + col] = v;
                else
                    out[(size_t)row * CH + col] = __float2bfloat16(v);
            }
        }
    }
}

// Grid per GEMM: (4, 64) = 256 blocks (1/CU).  XCD chunk = 8 M-panels x 4
// N-tiles -> per-XCD footprint/k-step ~384 KB << 4 MiB L2.
__device__ __forceinline__ void gemm_tile256(int& m0, int& n0) {
    int bid = blockIdx.y * 4 + blockIdx.x;       // [0,256)
    int swz = (bid & 7) * 32 + (bid >> 3);
    m0 = (swz >> 2) * 256;
    n0 = (swz & 3) * 256;
}

__global__ __launch_bounds__(512, 2) void gemm_qk256(
    const __hip_bfloat16* __restrict__ A0, const __hip_bfloat16* __restrict__ W0,
    const float* __restrict__ b0, __hip_bfloat16* __restrict__ o0, float alpha0,
    const __hip_bfloat16* __restrict__ A1, const __hip_bfloat16* __restrict__ W1,
    const float* __restrict__ b1, __hip_bfloat16* __restrict__ o1)
{
    __shared__ alignas(16) __hip_bfloat16 sm[65536];   // 128 KiB
    int m0, n0; gemm_tile256(m0, n0);
    if (blockIdx.z == 0)
        gemm_body256<__hip_bfloat16>(A0, W0, b0, o0, alpha0, m0, n0, sm);
    else
        gemm_body256<__hip_bfloat16>(A1, W1, b1, o1, 1.0f, m0, n0, sm);
}

template<typename OT>
__global__ __launch_bounds__(512, 2) void gemm_one256(
    const __hip_bfloat16* __restrict__ A, const __hip_bfloat16* __restrict__ Wb,
    const float* __restrict__ bias, OT* __restrict__ out)
{
    __shared__ alignas(16) __hip_bfloat16 sm[65536];   // 128 KiB
    int m0, n0; gemm_tile256(m0, n0);
    gemm_body256<OT>(A, Wb, bias, out, 1.0f, m0, n0, sm);
}

// One workgroup per (b, h, block-of-64-queries). Window of 192 keys
// starting at t0-64 (clamped loads, analytic masking).
__global__ __launch_bounds__(256) void attn_kernel(
    const __hip_bfloat16* __restrict__ qg,
    const __hip_bfloat16* __restrict__ kg,
    const __hip_bfloat16* __restrict__ vg,
    __hip_bfloat16* __restrict__ ctx)
{
    __shared__ alignas(16) char smem[62464];
    auto qs = reinterpret_cast<__hip_bfloat16(*)[72]>(smem);
    auto ks = reinterpret_cast<__hip_bfloat16(*)[72]>(smem + 9216);
    auto vt = reinterpret_cast<__hip_bfloat16(*)[200]>(smem + 36864);
    auto ps = reinterpret_cast<__hip_bfloat16(*)[200]>(smem);

    const int blk = xcd_swz(blockIdx.x, BATCH * NH * NBL);
    const int n = blk & (NBL - 1);
    const int h = (blk >> 7) & (NH - 1);
    const int b = blk >> 11;
    const int t0  = n * BLK;
    const int kst = t0 - 64;
    const int tid = threadIdx.x;
    const size_t baseBH = (size_t)b * SEQ * CH + (size_t)h * DH;

    #pragma unroll
    for (int it = 0; it < 2; it++) {
        int c = tid + it * 256;
        int row = c >> 3, seg = c & 7;
        *reinterpret_cast<uint4*>(&qs[row][seg * 8]) =
            *reinterpret_cast<const uint4*>(qg + baseBH + (size_t)(t0 + row) * CH + seg * 8);
    }
    #pragma unroll
    for (int it = 0; it < 6; it++) {
        int c = tid + it * 256;
        int row = c >> 3, seg = c & 7;
        int tr = kst + row; tr = tr < 0 ? 0 : (tr >= SEQ ? SEQ - 1 : tr);
        *reinterpret_cast<uint4*>(&ks[row][seg * 8]) =
            *reinterpret_cast<const uint4*>(kg + baseBH + (size_t)tr * CH + seg * 8);
    }
    #pragma unroll
    for (int it = 0; it < 6; it++) {
        int c = tid + it * 256;
        int j = c % WIN, seg = c / WIN;
        int tr = kst + j; tr = tr < 0 ? 0 : (tr >= SEQ ? SEQ - 1 : tr);
        Pack8 p;
        p.u = *reinterpret_cast<const uint4*>(vg + baseBH + (size_t)tr * CH + seg * 8);
        #pragma unroll
        for (int e = 0; e < 8; e++) vt[seg * 8 + e][j] = p.h[e];
    }
    __syncthreads();

    const int wid = tid >> 6, lane = tid & 63, quad = lane >> 4, l16 = lane & 15;

    f32x4 sc[12];
    #pragma unroll
    for (int j = 0; j < 12; j++) sc[j] = zero4();
    #pragma unroll
    for (int kk = 0; kk < 2; kk++) {
        bf16x8 aq = *reinterpret_cast<const bf16x8*>(&qs[wid * 16 + l16][kk * 32 + quad * 8]);
        #pragma unroll
        for (int j = 0; j < 12; j++) {
            bf16x8 bk = *reinterpret_cast<const bf16x8*>(&ks[j * 16 + l16][kk * 32 + quad * 8]);
            sc[j] = __builtin_amdgcn_mfma_f32_16x16x32_bf16(aq, bk, sc[j], 0, 0, 0);
        }
    }
    __syncthreads();

    #pragma unroll
    for (int r = 0; r < 4; r++) {
        float s[12];
        float mx = -3.0e38f;
        #pragma unroll
        for (int j = 0; j < 12; j++) {
            int col = j * 16 + l16;
            int tr = kst + col;
            bool valid = (tr >= 0) && (tr < SEQ);
            s[j] = valid ? sc[j][r] : -3.0e38f;
            mx = fmaxf(mx, s[j]);
        }
        #pragma unroll
        for (int o = 1; o < 16; o <<= 1) mx = fmaxf(mx, __shfl_xor(mx, o, 64));
        float sum = 0.f;
        #pragma unroll
        for (int j = 0; j < 12; j++) {
            float e = __expf(s[j] - mx);
            s[j] = e;
            sum += e;
        }
        #pragma unroll
        for (int o = 1; o < 16; o <<= 1) sum += __shfl_xor(sum, o, 64);
        const float inv = 1.f / sum;
        const int row = wid * 16 + quad * 4 + r;
        #pragma unroll
        for (int j = 0; j < 12; j++)
            ps[row][j * 16 + l16] = __float2bfloat16(s[j] * inv);
    }
    __syncthreads();

    f32x4 oa[4];
    #pragma unroll
    for (int j = 0; j < 4; j++) oa[j] = zero4();
    #pragma unroll
    for (int kk = 0; kk < 6; kk++) {
        bf16x8 ap = *reinterpret_cast<const bf16x8*>(&ps[wid * 16 + l16][kk * 32 + quad * 8]);
        #pragma unroll
        for (int j = 0; j < 4; j++) {
            bf16x8 bv = *reinterpret_cast<const bf16x8*>(&vt[j * 16 + l16][kk * 32 + quad * 8]);
            oa[j] = __builtin_amdgcn_mfma_f32_16x16x32_bf16(ap, bv, oa[j], 0, 0, 0);
        }
    }
    #pragma unroll
    for (int j = 0; j < 4; j++) {
        const int d = j * 16 + l16;
        #pragma unroll
        for (int r = 0; r < 4; r++) {
            const int i = wid * 16 + quad * 4 + r;
            ctx[baseBH + (size_t)(t0 + i) * CH + d] = __float2bfloat16(oa[j][r]);
        }
    }
}

extern "C" void kernel_launch(void* const* d_in, const int* in_sizes, int n_in,
                              void* d_out, int out_size, void* d_ws, size_t ws_size,
                              hipStream_t stream)
{
    const float* query = (const float*)d_in[0];
    const float* key_i = (const float*)d_in[1];
    const float* value = (const float*)d_in[2];
    const float* Wq = (const float*)d_in[3];
    const float* bq = (const float*)d_in[4];
    const float* Wk = (const float*)d_in[5];
    const float* bk = (const float*)d_in[6];
    const float* Wv = (const float*)d_in[7];
    const float* bv = (const float*)d_in[8];
    const float* Wo = (const float*)d_in[9];
    const float* bo = (const float*)d_in[10];
    float* out = (float*)d_out;

    const size_t NELEM = (size_t)MR * CH;   // 16,777,216
    const size_t WELEM = (size_t)CH * CH;   // 1,048,576

    __hip_bfloat16* S0 = (__hip_bfloat16*)d_ws;
    __hip_bfloat16* S1 = S0 + NELEM;
    __hip_bfloat16* S2 = S1 + NELEM;
    __hip_bfloat16* S3 = S2 + NELEM;
    __hip_bfloat16* wqb = S3;
    __hip_bfloat16* wkb = S3 + WELEM;
    __hip_bfloat16* wvb = S3 + 2 * WELEM;
    __hip_bfloat16* wob = S3 + 3 * WELEM;

    __hip_bfloat16* xq = (__hip_bfloat16*)d_out;
    __hip_bfloat16* xk = xq + NELEM;
    __hip_bfloat16* vb = (__hip_bfloat16*)d_out;
    __hip_bfloat16* qb = S1;
    __hip_bfloat16* kb = S2;
    __hip_bfloat16* cb = S0;

    const int nA8 = (int)(NELEM / 8);
    const int nW8 = (int)(WELEM / 8);

    pack_bf16<<<nA8 / 256, 256, 0, stream>>>(query, xq, nA8);
    pack_bf16<<<nA8 / 256, 256, 0, stream>>>(key_i, xk, nA8);
    pack_bf16<<<nA8 / 256, 256, 0, stream>>>(value, S0, nA8);
    pack_bf16<<<nW8 / 256, 256, 0, stream>>>(Wq, wqb, nW8);
    pack_bf16<<<nW8 / 256, 256, 0, stream>>>(Wk, wkb, nW8);
    pack_bf16<<<nW8 / 256, 256, 0, stream>>>(Wv, wvb, nW8);
    pack_bf16<<<nW8 / 256, 256, 0, stream>>>(Wo, wob, nW8);

    dim3 ggrid(CH / 256, MR / 256);         // (4, 64)
    dim3 qkgrid(CH / 256, MR / 256, 2);     // 512 blocks

    gemm_qk256<<<qkgrid, 512, 0, stream>>>(xq, wqb, bq, qb, 0.125f,
                                           xk, wkb, bk, kb);
    gemm_one256<__hip_bfloat16><<<ggrid, 512, 0, stream>>>(S0, wvb, bv, vb);

    attn_kernel<<<BATCH * NH * NBL, 256, 0, stream>>>(qb, kb, vb, cb);

    gemm_one256<float><<<ggrid, 512, 0, stream>>>(cb, wob, bo, out);
}

// Round 5
// 428.083 us; speedup vs baseline: 1.0484x; 1.0484x over previous
//
#include <hip/hip_runtime.h>
#include <hip/hip_bf16.h>
#include <type_traits>

#define BATCH 2
#define SEQ   8192
#define CH    1024
#define NH    16
#define BLK   64
#define WIN   192
#define NBL   128
#define DH    64
#define MR    (BATCH*SEQ)   // 16384

typedef __bf16 bf16x8 __attribute__((ext_vector_type(8)));
typedef float  f32x4  __attribute__((ext_vector_type(4)));

__device__ __forceinline__ f32x4 zero4() {
    f32x4 z; z[0]=0.f; z[1]=0.f; z[2]=0.f; z[3]=0.f; return z;
}

union Pack8 { __hip_bfloat16 h[8]; uint4 u; };

typedef const __attribute__((address_space(1))) unsigned int* gas_ptr;
typedef       __attribute__((address_space(3))) unsigned int* las_ptr;

__device__ __forceinline__ void gload_lds16(const __hip_bfloat16* g, __hip_bfloat16* l) {
    __builtin_amdgcn_global_load_lds((gas_ptr)(const void*)g, (las_ptr)(void*)l, 16, 0, 0);
}

__device__ __forceinline__ int xcd_swz(int bid, int nwg) {
    return (bid & 7) * (nwg >> 3) + (bid >> 3);
}

// ---- fused fp32 -> bf16 pack for all 7 tensors (1 launch instead of 7)
__global__ __launch_bounds__(256) void pack_all(
    const float* __restrict__ q,  const float* __restrict__ k,
    const float* __restrict__ v,
    const float* __restrict__ wq, const float* __restrict__ wk,
    const float* __restrict__ wv, const float* __restrict__ wo,
    __hip_bfloat16* __restrict__ xq, __hip_bfloat16* __restrict__ xk,
    __hip_bfloat16* __restrict__ xv,
    __hip_bfloat16* __restrict__ wqb, __hip_bfloat16* __restrict__ wkb,
    __hip_bfloat16* __restrict__ wvb, __hip_bfloat16* __restrict__ wob)
{
    const int NA8B = (MR * CH / 8) / 256;   // 8192 blocks per activation
    const int NW8B = (CH * CH / 8) / 256;   // 512 per weight
    int bid = blockIdx.x;
    const float* src;
    __hip_bfloat16* dst;
    int rel;
    if (bid < 3 * NA8B) {
        int t = bid / NA8B; rel = bid - t * NA8B;
        src = (t == 0) ? q : (t == 1) ? k : v;
        dst = (t == 0) ? xq : (t == 1) ? xk : xv;
    } else {
        int b2 = bid - 3 * NA8B;
        int t = b2 / NW8B; rel = b2 - t * NW8B;
        src = (t == 0) ? wq : (t == 1) ? wk : (t == 2) ? wv : wo;
        dst = (t == 0) ? wqb : (t == 1) ? wkb : (t == 2) ? wvb : wob;
    }
    int i = rel * 256 + threadIdx.x;
    const float4* s = reinterpret_cast<const float4*>(src);
    float4 a = s[2 * i], b = s[2 * i + 1];
    Pack8 p;
    p.h[0] = __float2bfloat16(a.x); p.h[1] = __float2bfloat16(a.y);
    p.h[2] = __float2bfloat16(a.z); p.h[3] = __float2bfloat16(a.w);
    p.h[4] = __float2bfloat16(b.x); p.h[5] = __float2bfloat16(b.y);
    p.h[6] = __float2bfloat16(b.z); p.h[7] = __float2bfloat16(b.w);
    reinterpret_cast<uint4*>(dst)[i] = p.u;
}

// =====================================================================
// 256x256 GEMM, BK=64, 8 waves (2M x 4N), 4-phase-per-tile schedule
// (unchanged from R4: 859 TF, MfmaUtil ~35%, 0 bank conflicts).
// =====================================================================

__device__ __forceinline__ void stage_half(
    const __hip_bfloat16* __restrict__ g, int goff,
    __hip_bfloat16* sm, int loff, int tid)
{
    gload_lds16(g + goff,            sm + loff + tid * 8);
    gload_lds16(g + goff + 128 * CH, sm + loff + (tid + 512) * 8);
}

#define SB0 __builtin_amdgcn_sched_barrier(0)
#define LGKM0 do { asm volatile("s_waitcnt lgkmcnt(0)" ::: "memory"); \
                   __builtin_amdgcn_sched_barrier(0); } while (0)
#define VMCNT(n) do { asm volatile("s_waitcnt vmcnt(" #n ")" ::: "memory"); \
                      __builtin_amdgcn_sched_barrier(0); } while (0)

template<int MH, bool RB>
__device__ __forceinline__ void phase_reads(
    const __hip_bfloat16* Ak, const __hip_bfloat16* Bk,
    int aoff, int boff, bf16x8 (&af)[4], bf16x8 (&bfk)[4])
{
    if constexpr (RB) {
        #pragma unroll
        for (int j = 0; j < 4; ++j)
            bfk[j] = *reinterpret_cast<const bf16x8*>(Bk + boff + j * 512);
    }
    #pragma unroll
    for (int i = 0; i < 4; ++i)
        af[i] = *reinterpret_cast<const bf16x8*>(Ak + aoff + (MH * 4 + i) * 512);
}

template<int MH>
__device__ __forceinline__ void phase_mfma16(
    const bf16x8 (&af)[4], const bf16x8 (&bfk)[4], f32x4 (&acc)[8][4])
{
    __builtin_amdgcn_s_setprio(1);
    #pragma unroll
    for (int i = 0; i < 4; ++i)
        #pragma unroll
        for (int j = 0; j < 4; ++j)
            acc[MH * 4 + i][j] = __builtin_amdgcn_mfma_f32_16x16x32_bf16(
                af[i], bfk[j], acc[MH * 4 + i][j], 0, 0, 0);
    __builtin_amdgcn_s_setprio(0);
}

template<typename OT>
__device__ __forceinline__ void gemm_body256(
    const __hip_bfloat16* __restrict__ A, const __hip_bfloat16* __restrict__ Wb,
    const float* __restrict__ bias, OT* __restrict__ out, float alpha,
    int m0, int n0, __hip_bfloat16* sm)
{
    const int tid  = threadIdx.x;
    const int wid  = tid >> 6;
    const int lane = tid & 63;
    const int quad = lane >> 4;
    const int l16  = lane & 15;
    const int wr   = wid >> 2, wc = wid & 3;   // 2 x 4 wave grid, 128x64 out each

    const int r0 = tid >> 2;
    const int s0 = (tid & 3) ^ ((tid >> 3) & 3);
    const int offA0 = (m0 + r0) * CH + s0 * 8;
    const int offB0 = (n0 + r0) * CH + s0 * 8;

    const int cq   = quad ^ ((l16 >> 1) & 3);
    const int aoff = ((wr * 128 + l16) * 4 + cq) * 8;
    const int boff = ((wc * 64  + l16) * 4 + cq) * 8;

    f32x4 acc[8][4];
    #pragma unroll
    for (int i = 0; i < 8; ++i)
        #pragma unroll
        for (int j = 0; j < 4; ++j) acc[i][j] = zero4();

    stage_half(A,  offA0,      sm, 0,             tid);
    stage_half(Wb, offB0,      sm, 32768,         tid);
    stage_half(A,  offA0 + 32, sm, 8192,          tid);
    stage_half(Wb, offB0 + 32, sm, 32768 + 8192,  tid);
    VMCNT(4);
    __builtin_amdgcn_s_barrier();
    SB0;

    bf16x8 af[4], bfk[4];

    #pragma unroll 1
    for (int t = 0; t < 15; ++t) {
        const int cur = t & 1, nb = cur ^ 1;
        const int kn  = (t + 1) * 64;
        const __hip_bfloat16* As_ = sm + cur * 16384;
        const __hip_bfloat16* Bs_ = sm + 32768 + cur * 16384;

        phase_reads<0, true>(As_, Bs_, aoff, boff, af, bfk);
        stage_half(A, offA0 + kn, sm, nb * 16384, tid);
        SB0;
        __builtin_amdgcn_s_barrier();
        LGKM0;
        phase_mfma16<0>(af, bfk, acc);
        __builtin_amdgcn_s_barrier();

        phase_reads<1, false>(As_, Bs_, aoff, boff, af, bfk);
        stage_half(Wb, offB0 + kn, sm, 32768 + nb * 16384, tid);
        SB0;
        __builtin_amdgcn_s_barrier();
        LGKM0;
        phase_mfma16<1>(af, bfk, acc);
        VMCNT(4);
        __builtin_amdgcn_s_barrier();

        phase_reads<0, true>(As_ + 8192, Bs_ + 8192, aoff, boff, af, bfk);
        stage_half(A, offA0 + kn + 32, sm, nb * 16384 + 8192, tid);
        SB0;
        __builtin_amdgcn_s_barrier();
        LGKM0;
        phase_mfma16<0>(af, bfk, acc);
        __builtin_amdgcn_s_barrier();

        phase_reads<1, false>(As_ + 8192, Bs_ + 8192, aoff, boff, af, bfk);
        stage_half(Wb, offB0 + kn + 32, sm, 32768 + nb * 16384 + 8192, tid);
        SB0;
        __builtin_amdgcn_s_barrier();
        LGKM0;
        phase_mfma16<1>(af, bfk, acc);
        VMCNT(4);
        __builtin_amdgcn_s_barrier();
    }

    {
        const __hip_bfloat16* As_ = sm + 16384;
        const __hip_bfloat16* Bs_ = sm + 32768 + 16384;

        phase_reads<0, true>(As_, Bs_, aoff, boff, af, bfk);
        SB0;
        __builtin_amdgcn_s_barrier();
        LGKM0;
        phase_mfma16<0>(af, bfk, acc);
        __builtin_amdgcn_s_barrier();

        phase_reads<1, false>(As_, Bs_, aoff, boff, af, bfk);
        SB0;
        __builtin_amdgcn_s_barrier();
        LGKM0;
        phase_mfma16<1>(af, bfk, acc);
        VMCNT(0);
        __builtin_amdgcn_s_barrier();

        phase_reads<0, true>(As_ + 8192, Bs_ + 8192, aoff, boff, af, bfk);
        SB0;
        __builtin_amdgcn_s_barrier();
        LGKM0;
        phase_mfma16<0>(af, bfk, acc);
        __builtin_amdgcn_s_barrier();

        phase_reads<1, false>(As_ + 8192, Bs_ + 8192, aoff, boff, af, bfk);
        SB0;
        __builtin_amdgcn_s_barrier();
        LGKM0;
        phase_mfma16<1>(af, bfk, acc);
    }

    #pragma unroll
    for (int j = 0; j < 4; ++j) {
        const int col = n0 + wc * 64 + j * 16 + l16;
        const float bv = bias[col];
        #pragma unroll
        for (int i = 0; i < 8; ++i) {
            #pragma unroll
            for (int r = 0; r < 4; ++r) {
                const int row = m0 + wr * 128 + i * 16 + quad * 4 + r;
                float v = alpha * (acc[i][j][r] + bv);
                if constexpr (std::is_same<OT, float>::value)
                    out[(size_t)row * CH + col] = v;
                else
                    out[(size_t)row * CH + col] = __float2bfloat16(v);
            }
        }
    }
}

__device__ __forceinline__ void gemm_tile256(int& m0, int& n0) {
    int bid = blockIdx.y * 4 + blockIdx.x;       // [0,256)
    int swz = (bid & 7) * 32 + (bid >> 3);
    m0 = (swz >> 2) * 256;
    n0 = (swz & 3) * 256;
}

__global__ __launch_bounds__(512, 2) void gemm_qk256(
    const __hip_bfloat16* __restrict__ A0, const __hip_bfloat16* __restrict__ W0,
    const float* __restrict__ b0, __hip_bfloat16* __restrict__ o0, float alpha0,
    const __hip_bfloat16* __restrict__ A1, const __hip_bfloat16* __restrict__ W1,
    const float* __restrict__ b1, __hip_bfloat16* __restrict__ o1)
{
    __shared__ alignas(16) __hip_bfloat16 sm[65536];   // 128 KiB
    int m0, n0; gemm_tile256(m0, n0);
    if (blockIdx.z == 0)
        gemm_body256<__hip_bfloat16>(A0, W0, b0, o0, alpha0, m0, n0, sm);
    else
        gemm_body256<__hip_bfloat16>(A1, W1, b1, o1, 1.0f, m0, n0, sm);
}

template<typename OT>
__global__ __launch_bounds__(512, 2) void gemm_one256(
    const __hip_bfloat16* __restrict__ A, const __hip_bfloat16* __restrict__ Wb,
    const float* __restrict__ bias, OT* __restrict__ out)
{
    __shared__ alignas(16) __hip_bfloat16 sm[65536];   // 128 KiB
    int m0, n0; gemm_tile256(m0, n0);
    gemm_body256<OT>(A, Wb, bias, out, 1.0f, m0, n0, sm);
}

// ---------------------------------------------------------------------
// Attention: one workgroup per (b, h, 64-query block), window 192 keys
// at t0-64 (clamped loads, analytic masking).
// R5 changes: Q hoisted to registers (no qs staging / LDS roundtrip);
// LDS 62464 -> 53248 B => 3 blocks/CU (12 waves, +50% latency hiding).
// ps (softmax probs) overlays ks: K is dead after the QK barrier.
// ---------------------------------------------------------------------
__global__ __launch_bounds__(256, 3) void attn_kernel(
    const __hip_bfloat16* __restrict__ qg,
    const __hip_bfloat16* __restrict__ kg,
    const __hip_bfloat16* __restrict__ vg,
    __hip_bfloat16* __restrict__ ctx)
{
    __shared__ alignas(16) char smem[53248];
    auto ks = reinterpret_cast<__hip_bfloat16(*)[72]>(smem);            // [192][72]
    auto vt = reinterpret_cast<__hip_bfloat16(*)[200]>(smem + 27648);   // [64][200]
    auto ps = reinterpret_cast<__hip_bfloat16(*)[200]>(smem);           // [64][200] (over ks)

    const int blk = xcd_swz(blockIdx.x, BATCH * NH * NBL);
    const int n = blk & (NBL - 1);
    const int h = (blk >> 7) & (NH - 1);
    const int b = blk >> 11;
    const int t0  = n * BLK;
    const int kst = t0 - 64;
    const int tid = threadIdx.x;
    const size_t baseBH = (size_t)b * SEQ * CH + (size_t)h * DH;

    const int wid = tid >> 6, lane = tid & 63, quad = lane >> 4, l16 = lane & 15;

    // Q direct to registers (same fragment mapping as the old qs path)
    const __hip_bfloat16* qrow = qg + baseBH + (size_t)(t0 + wid * 16 + l16) * CH + quad * 8;
    bf16x8 aq0 = *reinterpret_cast<const bf16x8*>(qrow);
    bf16x8 aq1 = *reinterpret_cast<const bf16x8*>(qrow + 32);

    #pragma unroll
    for (int it = 0; it < 6; it++) {
        int c = tid + it * 256;
        int row = c >> 3, seg = c & 7;
        int tr = kst + row; tr = tr < 0 ? 0 : (tr >= SEQ ? SEQ - 1 : tr);
        *reinterpret_cast<uint4*>(&ks[row][seg * 8]) =
            *reinterpret_cast<const uint4*>(kg + baseBH + (size_t)tr * CH + seg * 8);
    }
    #pragma unroll
    for (int it = 0; it < 6; it++) {
        int c = tid + it * 256;
        int j = c % WIN, seg = c / WIN;
        int tr = kst + j; tr = tr < 0 ? 0 : (tr >= SEQ ? SEQ - 1 : tr);
        Pack8 p;
        p.u = *reinterpret_cast<const uint4*>(vg + baseBH + (size_t)tr * CH + seg * 8);
        #pragma unroll
        for (int e = 0; e < 8; e++) vt[seg * 8 + e][j] = p.h[e];
    }
    __syncthreads();

    f32x4 sc[12];
    #pragma unroll
    for (int j = 0; j < 12; j++) sc[j] = zero4();
    #pragma unroll
    for (int j = 0; j < 12; j++) {
        bf16x8 bk0 = *reinterpret_cast<const bf16x8*>(&ks[j * 16 + l16][quad * 8]);
        sc[j] = __builtin_amdgcn_mfma_f32_16x16x32_bf16(aq0, bk0, sc[j], 0, 0, 0);
        bf16x8 bk1 = *reinterpret_cast<const bf16x8*>(&ks[j * 16 + l16][32 + quad * 8]);
        sc[j] = __builtin_amdgcn_mfma_f32_16x16x32_bf16(aq1, bk1, sc[j], 0, 0, 0);
    }
    __syncthreads();

    #pragma unroll
    for (int r = 0; r < 4; r++) {
        float s[12];
        float mx = -3.0e38f;
        #pragma unroll
        for (int j = 0; j < 12; j++) {
            int col = j * 16 + l16;
            int tr = kst + col;
            bool valid = (tr >= 0) && (tr < SEQ);
            s[j] = valid ? sc[j][r] : -3.0e38f;
            mx = fmaxf(mx, s[j]);
        }
        #pragma unroll
        for (int o = 1; o < 16; o <<= 1) mx = fmaxf(mx, __shfl_xor(mx, o, 64));
        float sum = 0.f;
        #pragma unroll
        for (int j = 0; j < 12; j++) {
            float e = __expf(s[j] - mx);
            s[j] = e;
            sum += e;
        }
        #pragma unroll
        for (int o = 1; o < 16; o <<= 1) sum += __shfl_xor(sum, o, 64);
        const float inv = 1.f / sum;
        const int row = wid * 16 + quad * 4 + r;
        #pragma unroll
        for (int j = 0; j < 12; j++)
            ps[row][j * 16 + l16] = __float2bfloat16(s[j] * inv);
    }
    __syncthreads();

    f32x4 oa[4];
    #pragma unroll
    for (int j = 0; j < 4; j++) oa[j] = zero4();
    #pragma unroll
    for (int kk = 0; kk < 6; kk++) {
        bf16x8 ap = *reinterpret_cast<const bf16x8*>(&ps[wid * 16 + l16][kk * 32 + quad * 8]);
        #pragma unroll
        for (int j = 0; j < 4; j++) {
            bf16x8 bv = *reinterpret_cast<const bf16x8*>(&vt[j * 16 + l16][kk * 32 + quad * 8]);
            oa[j] = __builtin_amdgcn_mfma_f32_16x16x32_bf16(ap, bv, oa[j], 0, 0, 0);
        }
    }
    #pragma unroll
    for (int j = 0; j < 4; j++) {
        const int d = j * 16 + l16;
        #pragma unroll
        for (int r = 0; r < 4; r++) {
            const int i = wid * 16 + quad * 4 + r;
            ctx[baseBH + (size_t)(t0 + i) * CH + d] = __float2bfloat16(oa[j][r]);
        }
    }
}

extern "C" void kernel_launch(void* const* d_in, const int* in_sizes, int n_in,
                              void* d_out, int out_size, void* d_ws, size_t ws_size,
                              hipStream_t stream)
{
    const float* query = (const float*)d_in[0];
    const float* key_i = (const float*)d_in[1];
    const float* value = (const float*)d_in[2];
    const float* Wq = (const float*)d_in[3];
    const float* bq = (const float*)d_in[4];
    const float* Wk = (const float*)d_in[5];
    const float* bk = (const float*)d_in[6];
    const float* Wv = (const float*)d_in[7];
    const float* bv = (const float*)d_in[8];
    const float* Wo = (const float*)d_in[9];
    const float* bo = (const float*)d_in[10];
    float* out = (float*)d_out;

    const size_t NELEM = (size_t)MR * CH;   // 16,777,216
    const size_t WELEM = (size_t)CH * CH;   // 1,048,576

    __hip_bfloat16* S0 = (__hip_bfloat16*)d_ws;
    __hip_bfloat16* S1 = S0 + NELEM;
    __hip_bfloat16* S2 = S1 + NELEM;
    __hip_bfloat16* S3 = S2 + NELEM;
    __hip_bfloat16* wqb = S3;
    __hip_bfloat16* wkb = S3 + WELEM;
    __hip_bfloat16* wvb = S3 + 2 * WELEM;
    __hip_bfloat16* wob = S3 + 3 * WELEM;

    __hip_bfloat16* xq = (__hip_bfloat16*)d_out;
    __hip_bfloat16* xk = xq + NELEM;
    __hip_bfloat16* vb = (__hip_bfloat16*)d_out;   // after QK-GEMM consumed xq/xk
    __hip_bfloat16* qb = S1;
    __hip_bfloat16* kb = S2;
    __hip_bfloat16* cb = S0;

    const int NA8B = (int)((NELEM / 8) / 256);   // 8192
    const int NW8B = (int)((WELEM / 8) / 256);   // 512

    pack_all<<<3 * NA8B + 4 * NW8B, 256, 0, stream>>>(
        query, key_i, value, Wq, Wk, Wv, Wo,
        xq, xk, S0, wqb, wkb, wvb, wob);

    dim3 ggrid(CH / 256, MR / 256);         // (4, 64)
    dim3 qkgrid(CH / 256, MR / 256, 2);     // 512 blocks

    gemm_qk256<<<qkgrid, 512, 0, stream>>>(xq, wqb, bq, qb, 0.125f,
                                           xk, wkb, bk, kb);
    gemm_one256<__hip_bfloat16><<<ggrid, 512, 0, stream>>>(S0, wvb, bv, vb);

    attn_kernel<<<BATCH * NH * NBL, 256, 0, stream>>>(qb, kb, vb, cb);

    gemm_one256<float><<<ggrid, 512, 0, stream>>>(cb, wob, bo, out);
}

// Round 6
// 425.342 us; speedup vs baseline: 1.0552x; 1.0064x over previous
//
#include <hip/hip_runtime.h>
#include <hip/hip_bf16.h>
#include <type_traits>

#define BATCH 2
#define SEQ   8192
#define CH    1024
#define NH    16
#define BLK   64
#define WIN   192
#define NBL   128
#define DH    64
#define MR    (BATCH*SEQ)   // 16384

typedef __bf16 bf16x8 __attribute__((ext_vector_type(8)));
typedef float  f32x4  __attribute__((ext_vector_type(4)));

__device__ __forceinline__ f32x4 zero4() {
    f32x4 z; z[0]=0.f; z[1]=0.f; z[2]=0.f; z[3]=0.f; return z;
}

union Pack8 { __hip_bfloat16 h[8]; uint4 u; };
union Pack4 { __hip_bfloat16 h[4]; uint2 u; };

typedef const __attribute__((address_space(1))) unsigned int* gas_ptr;
typedef       __attribute__((address_space(3))) unsigned int* las_ptr;

__device__ __forceinline__ void gload_lds16(const __hip_bfloat16* g, __hip_bfloat16* l) {
    __builtin_amdgcn_global_load_lds((gas_ptr)(const void*)g, (las_ptr)(void*)l, 16, 0, 0);
}

__device__ __forceinline__ int xcd_swz(int bid, int nwg) {
    return (bid & 7) * (nwg >> 3) + (bid >> 3);
}

// ---- fused fp32 -> bf16 pack, fully-coalesced per-instruction pattern:
// thread t loads float4 at [base+t] and [base+256+t] (1KB/wave contiguous
// each), stores uint2 (8B/lane) at the same indices.  (R5's s[2i]/s[2i+1]
// gave 32B lane stride -> 50% line utilization per instruction, 2.4 TB/s.)
__global__ __launch_bounds__(256) void pack_all(
    const float* __restrict__ q,  const float* __restrict__ k,
    const float* __restrict__ v,
    const float* __restrict__ wq, const float* __restrict__ wk,
    const float* __restrict__ wv, const float* __restrict__ wo,
    __hip_bfloat16* __restrict__ xq, __hip_bfloat16* __restrict__ xk,
    __hip_bfloat16* __restrict__ xv,
    __hip_bfloat16* __restrict__ wqb, __hip_bfloat16* __restrict__ wkb,
    __hip_bfloat16* __restrict__ wvb, __hip_bfloat16* __restrict__ wob)
{
    const int NA8B = (MR * CH / 8) / 256;   // 8192 blocks per activation
    const int NW8B = (CH * CH / 8) / 256;   // 512 per weight
    int bid = blockIdx.x;
    const float* src;
    __hip_bfloat16* dst;
    int rel;
    if (bid < 3 * NA8B) {
        int t = bid / NA8B; rel = bid - t * NA8B;
        src = (t == 0) ? q : (t == 1) ? k : v;
        dst = (t == 0) ? xq : (t == 1) ? xk : xv;
    } else {
        int b2 = bid - 3 * NA8B;
        int t = b2 / NW8B; rel = b2 - t * NW8B;
        src = (t == 0) ? wq : (t == 1) ? wk : (t == 2) ? wv : wo;
        dst = (t == 0) ? wqb : (t == 1) ? wkb : (t == 2) ? wvb : wob;
    }
    const int base = rel * 512;             // float4 units
    const float4* s = reinterpret_cast<const float4*>(src);
    uint2* d = reinterpret_cast<uint2*>(dst);
    float4 a = s[base + threadIdx.x];
    float4 b = s[base + 256 + threadIdx.x];
    Pack4 pa, pb;
    pa.h[0] = __float2bfloat16(a.x); pa.h[1] = __float2bfloat16(a.y);
    pa.h[2] = __float2bfloat16(a.z); pa.h[3] = __float2bfloat16(a.w);
    pb.h[0] = __float2bfloat16(b.x); pb.h[1] = __float2bfloat16(b.y);
    pb.h[2] = __float2bfloat16(b.z); pb.h[3] = __float2bfloat16(b.w);
    d[base + threadIdx.x]       = pa.u;
    d[base + 256 + threadIdx.x] = pb.u;
}

// =====================================================================
// 256x256 GEMM, BK=64, 8 waves (2M x 4N), 4-phase-per-tile schedule
// (unchanged from R4: 859 TF, MfmaUtil ~35%, 0 bank conflicts).
// =====================================================================

__device__ __forceinline__ void stage_half(
    const __hip_bfloat16* __restrict__ g, int goff,
    __hip_bfloat16* sm, int loff, int tid)
{
    gload_lds16(g + goff,            sm + loff + tid * 8);
    gload_lds16(g + goff + 128 * CH, sm + loff + (tid + 512) * 8);
}

#define SB0 __builtin_amdgcn_sched_barrier(0)
#define LGKM0 do { asm volatile("s_waitcnt lgkmcnt(0)" ::: "memory"); \
                   __builtin_amdgcn_sched_barrier(0); } while (0)
#define VMCNT(n) do { asm volatile("s_waitcnt vmcnt(" #n ")" ::: "memory"); \
                      __builtin_amdgcn_sched_barrier(0); } while (0)

template<int MH, bool RB>
__device__ __forceinline__ void phase_reads(
    const __hip_bfloat16* Ak, const __hip_bfloat16* Bk,
    int aoff, int boff, bf16x8 (&af)[4], bf16x8 (&bfk)[4])
{
    if constexpr (RB) {
        #pragma unroll
        for (int j = 0; j < 4; ++j)
            bfk[j] = *reinterpret_cast<const bf16x8*>(Bk + boff + j * 512);
    }
    #pragma unroll
    for (int i = 0; i < 4; ++i)
        af[i] = *reinterpret_cast<const bf16x8*>(Ak + aoff + (MH * 4 + i) * 512);
}

template<int MH>
__device__ __forceinline__ void phase_mfma16(
    const bf16x8 (&af)[4], const bf16x8 (&bfk)[4], f32x4 (&acc)[8][4])
{
    __builtin_amdgcn_s_setprio(1);
    #pragma unroll
    for (int i = 0; i < 4; ++i)
        #pragma unroll
        for (int j = 0; j < 4; ++j)
            acc[MH * 4 + i][j] = __builtin_amdgcn_mfma_f32_16x16x32_bf16(
                af[i], bfk[j], acc[MH * 4 + i][j], 0, 0, 0);
    __builtin_amdgcn_s_setprio(0);
}

template<typename OT>
__device__ __forceinline__ void gemm_body256(
    const __hip_bfloat16* __restrict__ A, const __hip_bfloat16* __restrict__ Wb,
    const float* __restrict__ bias, OT* __restrict__ out, float alpha,
    int m0, int n0, __hip_bfloat16* sm)
{
    const int tid  = threadIdx.x;
    const int wid  = tid >> 6;
    const int lane = tid & 63;
    const int quad = lane >> 4;
    const int l16  = lane & 15;
    const int wr   = wid >> 2, wc = wid & 3;   // 2 x 4 wave grid, 128x64 out each

    const int r0 = tid >> 2;
    const int s0 = (tid & 3) ^ ((tid >> 3) & 3);
    const int offA0 = (m0 + r0) * CH + s0 * 8;
    const int offB0 = (n0 + r0) * CH + s0 * 8;

    const int cq   = quad ^ ((l16 >> 1) & 3);
    const int aoff = ((wr * 128 + l16) * 4 + cq) * 8;
    const int boff = ((wc * 64  + l16) * 4 + cq) * 8;

    f32x4 acc[8][4];
    #pragma unroll
    for (int i = 0; i < 8; ++i)
        #pragma unroll
        for (int j = 0; j < 4; ++j) acc[i][j] = zero4();

    stage_half(A,  offA0,      sm, 0,             tid);
    stage_half(Wb, offB0,      sm, 32768,         tid);
    stage_half(A,  offA0 + 32, sm, 8192,          tid);
    stage_half(Wb, offB0 + 32, sm, 32768 + 8192,  tid);
    VMCNT(4);
    __builtin_amdgcn_s_barrier();
    SB0;

    bf16x8 af[4], bfk[4];

    #pragma unroll 1
    for (int t = 0; t < 15; ++t) {
        const int cur = t & 1, nb = cur ^ 1;
        const int kn  = (t + 1) * 64;
        const __hip_bfloat16* As_ = sm + cur * 16384;
        const __hip_bfloat16* Bs_ = sm + 32768 + cur * 16384;

        phase_reads<0, true>(As_, Bs_, aoff, boff, af, bfk);
        stage_half(A, offA0 + kn, sm, nb * 16384, tid);
        SB0;
        __builtin_amdgcn_s_barrier();
        LGKM0;
        phase_mfma16<0>(af, bfk, acc);
        __builtin_amdgcn_s_barrier();

        phase_reads<1, false>(As_, Bs_, aoff, boff, af, bfk);
        stage_half(Wb, offB0 + kn, sm, 32768 + nb * 16384, tid);
        SB0;
        __builtin_amdgcn_s_barrier();
        LGKM0;
        phase_mfma16<1>(af, bfk, acc);
        VMCNT(4);
        __builtin_amdgcn_s_barrier();

        phase_reads<0, true>(As_ + 8192, Bs_ + 8192, aoff, boff, af, bfk);
        stage_half(A, offA0 + kn + 32, sm, nb * 16384 + 8192, tid);
        SB0;
        __builtin_amdgcn_s_barrier();
        LGKM0;
        phase_mfma16<0>(af, bfk, acc);
        __builtin_amdgcn_s_barrier();

        phase_reads<1, false>(As_ + 8192, Bs_ + 8192, aoff, boff, af, bfk);
        stage_half(Wb, offB0 + kn + 32, sm, 32768 + nb * 16384 + 8192, tid);
        SB0;
        __builtin_amdgcn_s_barrier();
        LGKM0;
        phase_mfma16<1>(af, bfk, acc);
        VMCNT(4);
        __builtin_amdgcn_s_barrier();
    }

    {
        const __hip_bfloat16* As_ = sm + 16384;
        const __hip_bfloat16* Bs_ = sm + 32768 + 16384;

        phase_reads<0, true>(As_, Bs_, aoff, boff, af, bfk);
        SB0;
        __builtin_amdgcn_s_barrier();
        LGKM0;
        phase_mfma16<0>(af, bfk, acc);
        __builtin_amdgcn_s_barrier();

        phase_reads<1, false>(As_, Bs_, aoff, boff, af, bfk);
        SB0;
        __builtin_amdgcn_s_barrier();
        LGKM0;
        phase_mfma16<1>(af, bfk, acc);
        VMCNT(0);
        __builtin_amdgcn_s_barrier();

        phase_reads<0, true>(As_ + 8192, Bs_ + 8192, aoff, boff, af, bfk);
        SB0;
        __builtin_amdgcn_s_barrier();
        LGKM0;
        phase_mfma16<0>(af, bfk, acc);
        __builtin_amdgcn_s_barrier();

        phase_reads<1, false>(As_ + 8192, Bs_ + 8192, aoff, boff, af, bfk);
        SB0;
        __builtin_amdgcn_s_barrier();
        LGKM0;
        phase_mfma16<1>(af, bfk, acc);
    }

    #pragma unroll
    for (int j = 0; j < 4; ++j) {
        const int col = n0 + wc * 64 + j * 16 + l16;
        const float bv = bias[col];
        #pragma unroll
        for (int i = 0; i < 8; ++i) {
            #pragma unroll
            for (int r = 0; r < 4; ++r) {
                const int row = m0 + wr * 128 + i * 16 + quad * 4 + r;
                float v = alpha * (acc[i][j][r] + bv);
                if constexpr (std::is_same<OT, float>::value)
                    out[(size_t)row * CH + col] = v;
                else
                    out[(size_t)row * CH + col] = __float2bfloat16(v);
            }
        }
    }
}

__device__ __forceinline__ void gemm_tile256(int& m0, int& n0) {
    int bid = blockIdx.y * 4 + blockIdx.x;       // [0,256)
    int swz = (bid & 7) * 32 + (bid >> 3);
    m0 = (swz >> 2) * 256;
    n0 = (swz & 3) * 256;
}

__global__ __launch_bounds__(512, 2) void gemm_qk256(
    const __hip_bfloat16* __restrict__ A0, const __hip_bfloat16* __restrict__ W0,
    const float* __restrict__ b0, __hip_bfloat16* __restrict__ o0, float alpha0,
    const __hip_bfloat16* __restrict__ A1, const __hip_bfloat16* __restrict__ W1,
    const float* __restrict__ b1, __hip_bfloat16* __restrict__ o1)
{
    __shared__ alignas(16) __hip_bfloat16 sm[65536];   // 128 KiB
    int m0, n0; gemm_tile256(m0, n0);
    if (blockIdx.z == 0)
        gemm_body256<__hip_bfloat16>(A0, W0, b0, o0, alpha0, m0, n0, sm);
    else
        gemm_body256<__hip_bfloat16>(A1, W1, b1, o1, 1.0f, m0, n0, sm);
}

template<typename OT>
__global__ __launch_bounds__(512, 2) void gemm_one256(
    const __hip_bfloat16* __restrict__ A, const __hip_bfloat16* __restrict__ Wb,
    const float* __restrict__ bias, OT* __restrict__ out)
{
    __shared__ alignas(16) __hip_bfloat16 sm[65536];   // 128 KiB
    int m0, n0; gemm_tile256(m0, n0);
    gemm_body256<OT>(A, Wb, bias, out, 1.0f, m0, n0, sm);
}

// ---------------------------------------------------------------------
// Attention: one workgroup per (b, h, 64-query block), window 192 keys
// at t0-64 (clamped loads, analytic masking).  Q in registers; 3 blk/CU.
// R6: T14 split for V -- V global loads issued up-front into regs, the
// 48 scalar transpose-writes moved into the softmax window (LDS pipe
// drains under softmax VALU; pre-PV barrier covers the dependency).
// ps (softmax probs) overlays ks: K is dead after the QK barrier.
// ---------------------------------------------------------------------
__global__ __launch_bounds__(256, 3) void attn_kernel(
    const __hip_bfloat16* __restrict__ qg,
    const __hip_bfloat16* __restrict__ kg,
    const __hip_bfloat16* __restrict__ vg,
    __hip_bfloat16* __restrict__ ctx)
{
    __shared__ alignas(16) char smem[53248];
    auto ks = reinterpret_cast<__hip_bfloat16(*)[72]>(smem);            // [192][72]
    auto vt = reinterpret_cast<__hip_bfloat16(*)[200]>(smem + 27648);   // [64][200]
    auto ps = reinterpret_cast<__hip_bfloat16(*)[200]>(smem);           // [64][200] (over ks)

    const int blk = xcd_swz(blockIdx.x, BATCH * NH * NBL);
    const int n = blk & (NBL - 1);
    const int h = (blk >> 7) & (NH - 1);
    const int b = blk >> 11;
    const int t0  = n * BLK;
    const int kst = t0 - 64;
    const int tid = threadIdx.x;
    const size_t baseBH = (size_t)b * SEQ * CH + (size_t)h * DH;

    const int wid = tid >> 6, lane = tid & 63, quad = lane >> 4, l16 = lane & 15;

    // Q direct to registers
    const __hip_bfloat16* qrow = qg + baseBH + (size_t)(t0 + wid * 16 + l16) * CH + quad * 8;
    bf16x8 aq0 = *reinterpret_cast<const bf16x8*>(qrow);
    bf16x8 aq1 = *reinterpret_cast<const bf16x8*>(qrow + 32);

    // V loads issued early into regs (T14 issue-early / write-late)
    uint4 vreg[6];
    int vj[6], vseg[6];
    #pragma unroll
    for (int it = 0; it < 6; it++) {
        int c = tid + it * 256;
        vj[it] = c % WIN; vseg[it] = c / WIN;
        int tr = kst + vj[it]; tr = tr < 0 ? 0 : (tr >= SEQ ? SEQ - 1 : tr);
        vreg[it] = *reinterpret_cast<const uint4*>(vg + baseBH + (size_t)tr * CH + vseg[it] * 8);
    }

    // K staged to LDS
    #pragma unroll
    for (int it = 0; it < 6; it++) {
        int c = tid + it * 256;
        int row = c >> 3, seg = c & 7;
        int tr = kst + row; tr = tr < 0 ? 0 : (tr >= SEQ ? SEQ - 1 : tr);
        *reinterpret_cast<uint4*>(&ks[row][seg * 8]) =
            *reinterpret_cast<const uint4*>(kg + baseBH + (size_t)tr * CH + seg * 8);
    }
    __syncthreads();

    f32x4 sc[12];
    #pragma unroll
    for (int j = 0; j < 12; j++) sc[j] = zero4();
    #pragma unroll
    for (int j = 0; j < 12; j++) {
        bf16x8 bk0 = *reinterpret_cast<const bf16x8*>(&ks[j * 16 + l16][quad * 8]);
        sc[j] = __builtin_amdgcn_mfma_f32_16x16x32_bf16(aq0, bk0, sc[j], 0, 0, 0);
        bf16x8 bk1 = *reinterpret_cast<const bf16x8*>(&ks[j * 16 + l16][32 + quad * 8]);
        sc[j] = __builtin_amdgcn_mfma_f32_16x16x32_bf16(aq1, bk1, sc[j], 0, 0, 0);
    }
    __syncthreads();

    // V transpose-writes (LDS pipe) issue first, softmax VALU runs under them
    #pragma unroll
    for (int it = 0; it < 6; it++) {
        Pack8 p; p.u = vreg[it];
        #pragma unroll
        for (int e = 0; e < 8; e++) vt[vseg[it] * 8 + e][vj[it]] = p.h[e];
    }

    #pragma unroll
    for (int r = 0; r < 4; r++) {
        float s[12];
        float mx = -3.0e38f;
        #pragma unroll
        for (int j = 0; j < 12; j++) {
            int col = j * 16 + l16;
            int tr = kst + col;
            bool valid = (tr >= 0) && (tr < SEQ);
            s[j] = valid ? sc[j][r] : -3.0e38f;
            mx = fmaxf(mx, s[j]);
        }
        #pragma unroll
        for (int o = 1; o < 16; o <<= 1) mx = fmaxf(mx, __shfl_xor(mx, o, 64));
        float sum = 0.f;
        #pragma unroll
        for (int j = 0; j < 12; j++) {
            float e = __expf(s[j] - mx);
            s[j] = e;
            sum += e;
        }
        #pragma unroll
        for (int o = 1; o < 16; o <<= 1) sum += __shfl_xor(sum, o, 64);
        const float inv = 1.f / sum;
        const int row = wid * 16 + quad * 4 + r;
        #pragma unroll
        for (int j = 0; j < 12; j++)
            ps[row][j * 16 + l16] = __float2bfloat16(s[j] * inv);
    }
    __syncthreads();

    f32x4 oa[4];
    #pragma unroll
    for (int j = 0; j < 4; j++) oa[j] = zero4();
    #pragma unroll
    for (int kk = 0; kk < 6; kk++) {
        bf16x8 ap = *reinterpret_cast<const bf16x8*>(&ps[wid * 16 + l16][kk * 32 + quad * 8]);
        #pragma unroll
        for (int j = 0; j < 4; j++) {
            bf16x8 bv = *reinterpret_cast<const bf16x8*>(&vt[j * 16 + l16][kk * 32 + quad * 8]);
            oa[j] = __builtin_amdgcn_mfma_f32_16x16x32_bf16(ap, bv, oa[j], 0, 0, 0);
        }
    }
    #pragma unroll
    for (int j = 0; j < 4; j++) {
        const int d = j * 16 + l16;
        #pragma unroll
        for (int r = 0; r < 4; r++) {
            const int i = wid * 16 + quad * 4 + r;
            ctx[baseBH + (size_t)(t0 + i) * CH + d] = __float2bfloat16(oa[j][r]);
        }
    }
}

extern "C" void kernel_launch(void* const* d_in, const int* in_sizes, int n_in,
                              void* d_out, int out_size, void* d_ws, size_t ws_size,
                              hipStream_t stream)
{
    const float* query = (const float*)d_in[0];
    const float* key_i = (const float*)d_in[1];
    const float* value = (const float*)d_in[2];
    const float* Wq = (const float*)d_in[3];
    const float* bq = (const float*)d_in[4];
    const float* Wk = (const float*)d_in[5];
    const float* bk = (const float*)d_in[6];
    const float* Wv = (const float*)d_in[7];
    const float* bv = (const float*)d_in[8];
    const float* Wo = (const float*)d_in[9];
    const float* bo = (const float*)d_in[10];
    float* out = (float*)d_out;

    const size_t NELEM = (size_t)MR * CH;   // 16,777,216
    const size_t WELEM = (size_t)CH * CH;   // 1,048,576

    __hip_bfloat16* S0 = (__hip_bfloat16*)d_ws;
    __hip_bfloat16* S1 = S0 + NELEM;
    __hip_bfloat16* S2 = S1 + NELEM;
    __hip_bfloat16* S3 = S2 + NELEM;
    __hip_bfloat16* wqb = S3;
    __hip_bfloat16* wkb = S3 + WELEM;
    __hip_bfloat16* wvb = S3 + 2 * WELEM;
    __hip_bfloat16* wob = S3 + 3 * WELEM;

    __hip_bfloat16* xq = (__hip_bfloat16*)d_out;
    __hip_bfloat16* xk = xq + NELEM;
    __hip_bfloat16* vb = (__hip_bfloat16*)d_out;   // after QK-GEMM consumed xq/xk
    __hip_bfloat16* qb = S1;
    __hip_bfloat16* kb = S2;
    __hip_bfloat16* cb = S0;

    const int NA8B = (int)((NELEM / 8) / 256);   // 8192
    const int NW8B = (int)((WELEM / 8) / 256);   // 512

    pack_all<<<3 * NA8B + 4 * NW8B, 256, 0, stream>>>(
        query, key_i, value, Wq, Wk, Wv, Wo,
        xq, xk, S0, wqb, wkb, wvb, wob);

    dim3 ggrid(CH / 256, MR / 256);         // (4, 64)
    dim3 qkgrid(CH / 256, MR / 256, 2);     // 512 blocks

    gemm_qk256<<<qkgrid, 512, 0, stream>>>(xq, wqb, bq, qb, 0.125f,
                                           xk, wkb, bk, kb);
    gemm_one256<__hip_bfloat16><<<ggrid, 512, 0, stream>>>(S0, wvb, bv, vb);

    attn_kernel<<<BATCH * NH * NBL, 256, 0, stream>>>(qb, kb, vb, cb);

    gemm_one256<float><<<ggrid, 512, 0, stream>>>(cb, wob, bo, out);
}